// Round 6
// baseline (1183.713 us; speedup 1.0000x reference)
//
#include <hip/hip_runtime.h>

// ---------------------------------------------------------------------------
// SClusterFormer block for MI355X (gfx950).
// Round 6: 256x256 MLP GEMM, LDS kept within the 64 KB static envelope.
//   - gemm512: BM=BN=256, BK=32, 512 threads (8 waves 2Mx4N, wave tile
//     128x64), double-buffered LDS = 65536 B, 2-phase prefetch (round-3
//     proven body, T=512). 32 MFMA / 12 ds_read per wave per barrier-pair
//     (2x the 128^2 amortization that plateaued at MfmaUtil 18%).
//   - round-5's 128 KiB-LDS gemm256 removed (prime suspect for the
//     container failure: static __shared__ > 64 KB).
//   - everything else byte-identical to round 4's passed configuration.
// ---------------------------------------------------------------------------

typedef __attribute__((ext_vector_type(8))) short short8;
typedef __attribute__((ext_vector_type(4))) short short4v;
typedef __attribute__((ext_vector_type(4))) float floatx4;

// float -> bf16 bits, round-to-nearest-even (inputs finite)
static __device__ __forceinline__ short f2bf(float f) {
  union { float f; unsigned u; } a; a.f = f;
  unsigned r = a.u + 0x7fffu + ((a.u >> 16) & 1u);
  return (short)(r >> 16);
}

// async global->LDS, 16 bytes per lane. LDS dest must be wave-uniform base +
// lane*16 (our staging index is lane-contiguous per wave, so this holds).
static __device__ __forceinline__ void gload_lds16(const short* g, short* l) {
  __builtin_amdgcn_global_load_lds(
      (const __attribute__((address_space(1))) void*)g,
      (__attribute__((address_space(3))) void*)l, 16, 0, 0);
}

// ---------------------------------------------------------------------------
// f32 -> bf16 weight conversion (elementwise, float4 per thread)
__global__ __launch_bounds__(256) void cvt_f32_bf16(
    const float* __restrict__ in, short* __restrict__ out, int n4)
{
  int i = blockIdx.x * 256 + threadIdx.x;
  if (i >= n4) return;
  float4 v = reinterpret_cast<const float4*>(in)[i];
  short4v o;
  o[0] = f2bf(v.x); o[1] = f2bf(v.y); o[2] = f2bf(v.z); o[3] = f2bf(v.w);
  reinterpret_cast<short4v*>(out)[i] = o;
}

// ---------------------------------------------------------------------------
// LayerNorm over D=512, one wave per row, bf16 output.
__global__ __launch_bounds__(256) void ln_kernel(
    const float* __restrict__ x, const float* __restrict__ g,
    const float* __restrict__ b, short* __restrict__ out)
{
  const int wave = threadIdx.x >> 6, lane = threadIdx.x & 63;
  const size_t row = (size_t)blockIdx.x * 4 + wave;
  const float* xr = x + row * 512;
  const int c = lane * 8;
  float4 v0 = *reinterpret_cast<const float4*>(xr + c);
  float4 v1 = *reinterpret_cast<const float4*>(xr + c + 4);
  float xs[8] = {v0.x, v0.y, v0.z, v0.w, v1.x, v1.y, v1.z, v1.w};
  float s = 0.f, q = 0.f;
#pragma unroll
  for (int k = 0; k < 8; ++k) { s += xs[k]; q += xs[k] * xs[k]; }
#pragma unroll
  for (int off = 32; off; off >>= 1) {
    s += __shfl_xor(s, off);
    q += __shfl_xor(q, off);
  }
  const float mean = s * (1.0f / 512.0f);
  const float var  = q * (1.0f / 512.0f) - mean * mean;
  const float rstd = rsqrtf(var + 1e-5f);
  short8 o;
#pragma unroll
  for (int k = 0; k < 8; ++k)
    o[k] = f2bf((xs[k] - mean) * rstd * g[c + k] + b[c + k]);
  *reinterpret_cast<short8*>(out + row * 512 + c) = o;
}

// ---------------------------------------------------------------------------
// gemm_bt (4-wave): C[m,n] = epi( A[m,:] . W[n,:] + bias[n] )
//   A: bf16 [M,K] row-major, W: bf16 [N,K] row-major (B^T layout).
//   EPI 0: store f32   EPI 1: +resid, store f32   EPI 2: gelu, store bf16
// 256 threads; 2-phase double-buffered (round-3/4 proven form).
template<int BM, int BN, int WM, int WN, int EPI>
__global__ __launch_bounds__(256, 2) void gemm_bt(
    const short* __restrict__ A, const short* __restrict__ W,
    const float* __restrict__ bias, const float* __restrict__ resid,
    float* __restrict__ Cf, short* __restrict__ Cb,
    const int N, const int K)
{
  constexpr int BK = 32;                 // 4 chunks of 8 bf16 per row
  constexpr int T  = 256;
  constexpr int AC = (BM * BK / 8) / T;
  constexpr int WC = (BN * BK / 8) / T;
  __shared__ short Al[2][BM * BK];
  __shared__ short Wl[2][BN * BK];
  const int tid  = threadIdx.x;
  const int wave = tid >> 6;
  const int lane = tid & 63;
  constexpr int WCOLS = BN / WN;
  const int wm = (wave / WCOLS) * WM;
  const int wn = (wave % WCOLS) * WN;
  constexpr int MI = WM / 16, NJ = WN / 16;
  const int row0 = blockIdx.x * BM;
  const int col0 = blockIdx.y * BN;
  const int r  = lane & 15;
  const int kc = lane >> 4;

  floatx4 acc[MI][NJ];
#pragma unroll
  for (int i = 0; i < MI; ++i)
#pragma unroll
    for (int j = 0; j < NJ; ++j)
      acc[i][j] = (floatx4){0.f, 0.f, 0.f, 0.f};

  const short* Ab = A + (size_t)row0 * K;
  const short* Wb = W + (size_t)col0 * K;

  const short* aSrc[AC]; int aDst[AC];
#pragma unroll
  for (int u = 0; u < AC; ++u) {
    const int cc = u * T + tid;
    const int rr = cc >> 2, sl = cc & 3;
    const int co = sl ^ ((rr >> 1) & 3);
    aSrc[u] = Ab + (size_t)rr * K + co * 8;
    aDst[u] = cc * 8;
  }
  const short* wSrc[WC]; int wDst[WC];
#pragma unroll
  for (int u = 0; u < WC; ++u) {
    const int cc = u * T + tid;
    const int rr = cc >> 2, sl = cc & 3;
    const int co = sl ^ ((rr >> 1) & 3);
    wSrc[u] = Wb + (size_t)rr * K + co * 8;
    wDst[u] = cc * 8;
  }
  int aOff[MI], wOff[NJ];
#pragma unroll
  for (int i = 0; i < MI; ++i) {
    const int rt = wm + 16 * i + r;
    aOff[i] = rt * BK + ((kc ^ ((rt >> 1) & 3)) << 3);
  }
#pragma unroll
  for (int j = 0; j < NJ; ++j) {
    const int rt = wn + 16 * j + r;
    wOff[j] = rt * BK + ((kc ^ ((rt >> 1) & 3)) << 3);
  }

  auto stage = [&](int buf, int k0) {
#pragma unroll
    for (int u = 0; u < AC; ++u) gload_lds16(aSrc[u] + k0, &Al[buf][aDst[u]]);
#pragma unroll
    for (int u = 0; u < WC; ++u) gload_lds16(wSrc[u] + k0, &Wl[buf][wDst[u]]);
  };

  stage(0, 0);
  __syncthreads();
  int cur = 0;
  for (int k0 = BK; k0 <= K; k0 += BK) {
    if (k0 < K) stage(cur ^ 1, k0);
    short8 af[MI], wfr[NJ];
#pragma unroll
    for (int i = 0; i < MI; ++i)
      af[i] = *reinterpret_cast<const short8*>(&Al[cur][aOff[i]]);
#pragma unroll
    for (int j = 0; j < NJ; ++j)
      wfr[j] = *reinterpret_cast<const short8*>(&Wl[cur][wOff[j]]);
#pragma unroll
    for (int i = 0; i < MI; ++i)
#pragma unroll
      for (int j = 0; j < NJ; ++j)
        acc[i][j] = __builtin_amdgcn_mfma_f32_16x16x32_bf16(
            af[i], wfr[j], acc[i][j], 0, 0, 0);
    __syncthreads();
    cur ^= 1;
  }

#pragma unroll
  for (int i = 0; i < MI; ++i) {
#pragma unroll
    for (int j = 0; j < NJ; ++j) {
      const int col = col0 + wn + 16 * j + r;
      const float bv = bias[col];
#pragma unroll
      for (int t = 0; t < 4; ++t) {
        const int rowi = row0 + wm + 16 * i + (lane >> 4) * 4 + t;
        const size_t offo = (size_t)rowi * N + col;
        float v = acc[i][j][t] + bv;
        if (EPI == 0) {
          Cf[offo] = v;
        } else if (EPI == 1) {
          Cf[offo] = v + resid[offo];
        } else {
          v = 0.5f * v * (1.0f + erff(v * 0.70710678118654752f));
          Cb[offo] = f2bf(v);
        }
      }
    }
  }
}

// ---------------------------------------------------------------------------
// gemm512 (8-wave): 256x256 tile, BK=32, 512 threads (2Mx4N waves, wave tile
// 128x64 -> MI=8, NJ=4). LDS dbuf = 65536 B (within 64 KB envelope).
// Same 2-phase body and XOR swizzle as gemm_bt. 32 MFMA / 12 ds_read_b128
// per wave per barrier-pair.
//   EPI 1: +resid, store f32      EPI 2: gelu, store bf16
template<int EPI>
__global__ __launch_bounds__(512, 1) void gemm512(
    const short* __restrict__ A, const short* __restrict__ W,
    const float* __restrict__ bias, const float* __restrict__ resid,
    float* __restrict__ Cf, short* __restrict__ Cb,
    const int N, const int K)
{
  constexpr int BM = 256, BN = 256, BK = 32;
  constexpr int T  = 512;
  constexpr int AC = (BM * BK / 8) / T;   // 2
  constexpr int WC = (BN * BK / 8) / T;   // 2
  constexpr int WM = 128, WN = 64;
  constexpr int MI = WM / 16, NJ = WN / 16;   // 8, 4
  __shared__ short Al[2][BM * BK];        // 2 x 16 KB
  __shared__ short Wl[2][BN * BK];        // 2 x 16 KB  -> 64 KiB total
  const int tid  = threadIdx.x;
  const int wave = tid >> 6;              // 0..7
  const int lane = tid & 63;
  const int wm = (wave >> 2) * WM;        // 2 wave-rows of 128
  const int wn = (wave & 3) * WN;         // 4 wave-cols of 64
  const int row0 = blockIdx.x * BM;
  const int col0 = blockIdx.y * BN;
  const int r  = lane & 15;
  const int kc = lane >> 4;

  floatx4 acc[MI][NJ];
#pragma unroll
  for (int i = 0; i < MI; ++i)
#pragma unroll
    for (int j = 0; j < NJ; ++j)
      acc[i][j] = (floatx4){0.f, 0.f, 0.f, 0.f};

  const short* Ab = A + (size_t)row0 * K;
  const short* Wb = W + (size_t)col0 * K;

  const short* aSrc[AC]; int aDst[AC];
#pragma unroll
  for (int u = 0; u < AC; ++u) {
    const int cc = u * T + tid;
    const int rr = cc >> 2, sl = cc & 3;
    const int co = sl ^ ((rr >> 1) & 3);
    aSrc[u] = Ab + (size_t)rr * K + co * 8;
    aDst[u] = cc * 8;
  }
  const short* wSrc[WC]; int wDst[WC];
#pragma unroll
  for (int u = 0; u < WC; ++u) {
    const int cc = u * T + tid;
    const int rr = cc >> 2, sl = cc & 3;
    const int co = sl ^ ((rr >> 1) & 3);
    wSrc[u] = Wb + (size_t)rr * K + co * 8;
    wDst[u] = cc * 8;
  }
  int aOff[MI], wOff[NJ];
#pragma unroll
  for (int i = 0; i < MI; ++i) {
    const int rt = wm + 16 * i + r;
    aOff[i] = rt * BK + ((kc ^ ((rt >> 1) & 3)) << 3);
  }
#pragma unroll
  for (int j = 0; j < NJ; ++j) {
    const int rt = wn + 16 * j + r;
    wOff[j] = rt * BK + ((kc ^ ((rt >> 1) & 3)) << 3);
  }

  auto stage = [&](int buf, int k0) {
#pragma unroll
    for (int u = 0; u < AC; ++u) gload_lds16(aSrc[u] + k0, &Al[buf][aDst[u]]);
#pragma unroll
    for (int u = 0; u < WC; ++u) gload_lds16(wSrc[u] + k0, &Wl[buf][wDst[u]]);
  };

  stage(0, 0);
  __syncthreads();
  int cur = 0;
  for (int k0 = BK; k0 <= K; k0 += BK) {
    if (k0 < K) stage(cur ^ 1, k0);
    short8 af[MI], wfr[NJ];
#pragma unroll
    for (int i = 0; i < MI; ++i)
      af[i] = *reinterpret_cast<const short8*>(&Al[cur][aOff[i]]);
#pragma unroll
    for (int j = 0; j < NJ; ++j)
      wfr[j] = *reinterpret_cast<const short8*>(&Wl[cur][wOff[j]]);
#pragma unroll
    for (int i = 0; i < MI; ++i)
#pragma unroll
      for (int j = 0; j < NJ; ++j)
        acc[i][j] = __builtin_amdgcn_mfma_f32_16x16x32_bf16(
            af[i], wfr[j], acc[i][j], 0, 0, 0);
    __syncthreads();
    cur ^= 1;
  }

  // epilogue: col=lane&15, row=(lane>>4)*4+reg
#pragma unroll
  for (int i = 0; i < MI; ++i) {
#pragma unroll
    for (int j = 0; j < NJ; ++j) {
      const int col = col0 + wn + 16 * j + r;
      const float bv = bias[col];
#pragma unroll
      for (int t = 0; t < 4; ++t) {
        const int rowi = row0 + wm + 16 * i + kc * 4 + t;
        const size_t offo = (size_t)rowi * N + col;
        float v = acc[i][j][t] + bv;
        if (EPI == 1) {
          Cf[offo] = v + resid[offo];
        } else {
          v = 0.5f * v * (1.0f + erff(v * 0.70710678118654752f));
          Cb[offo] = f2bf(v);
        }
      }
    }
  }
}

// ---------------------------------------------------------------------------
// AdaptiveAvgPool 32x32 -> 4x4 per (b,h); writes normalized centers (cn) and
// pooled values (vcent). One block per bh, 384 threads = (m, c).
__global__ __launch_bounds__(384) void pool_kernel(
    const float* __restrict__ feat, const float* __restrict__ val,
    float* __restrict__ cn, float* __restrict__ vcent)
{
  const int bh = blockIdx.x;
  const int b = bh >> 3, h = bh & 7;
  const int t = threadIdx.x;        // 0..383
  const int m = t / 24, c = t % 24;
  const int cy = m >> 2, cx = m & 3;
  const size_t base = (size_t)b * 1024 * 192 + h * 24 + c;
  float sf = 0.f, sv = 0.f;
  for (int dy = 0; dy < 8; ++dy) {
    const int ny = (cy * 8 + dy) * 32 + cx * 8;
    for (int dx = 0; dx < 8; ++dx) {
      const size_t off = base + (size_t)(ny + dx) * 192;
      sf += feat[off];
      sv += val[off];
    }
  }
  sf *= (1.0f / 64.0f); sv *= (1.0f / 64.0f);
  __shared__ float cent[16][24];
  cent[m][c] = sf;
  vcent[(size_t)bh * 384 + t] = sv;
  __syncthreads();
  float nrm = 0.f;
#pragma unroll
  for (int k = 0; k < 24; ++k) nrm += cent[m][k] * cent[m][k];
  nrm = fmaxf(sqrtf(nrm), 1e-12f);
  cn[(size_t)bh * 384 + t] = sf / nrm;
}

// ---------------------------------------------------------------------------
// Per token: cosine sim vs 16 centers, leaky-relu, top-1 -> (value, index).
__global__ __launch_bounds__(256) void sim_kernel(
    const float* __restrict__ feat, const float* __restrict__ cn,
    const float* __restrict__ alpha_p, const float* __restrict__ beta_p,
    float* __restrict__ sval, int* __restrict__ sidx)
{
  const int bh = blockIdx.y;
  const int b = bh >> 3, h = bh & 7;
  __shared__ float cs[384];
  for (int i = threadIdx.x; i < 384; i += 256) cs[i] = cn[(size_t)bh * 384 + i];
  __syncthreads();
  const int n = blockIdx.x * 256 + threadIdx.x;
  const float* f = feat + (size_t)(b * 1024 + n) * 192 + h * 24;
  float v[24];
#pragma unroll
  for (int k = 0; k < 24; k += 4) {
    float4 t4 = *reinterpret_cast<const float4*>(f + k);
    v[k] = t4.x; v[k + 1] = t4.y; v[k + 2] = t4.z; v[k + 3] = t4.w;
  }
  float q = 0.f;
#pragma unroll
  for (int k = 0; k < 24; ++k) q += v[k] * v[k];
  const float inv = 1.0f / fmaxf(sqrtf(q), 1e-12f);
  const float alpha = alpha_p[0], beta = beta_p[0];
  float best = -3.4e38f; int bi = 0;
#pragma unroll
  for (int m = 0; m < 16; ++m) {
    float d = 0.f;
#pragma unroll
    for (int k = 0; k < 24; ++k) d += cs[m * 24 + k] * v[k];
    float s = beta + alpha * (d * inv);
    s = (s < 0.f) ? 0.2f * s : s;            // LeakyReLU(0.2)
    if (s > best) { best = s; bi = m; }      // strict > == first-max (jnp.argmax)
  }
  sval[(size_t)bh * 1024 + n] = best;
  sidx[(size_t)bh * 1024 + n] = bi;
}

// ---------------------------------------------------------------------------
// agg[bh,m,:] = (sum_{n: idx=m} s_n * vh[n,:] + vcent[m,:]) / (count_m + 1)
__global__ __launch_bounds__(256) void agg_kernel(
    const float* __restrict__ val, const float* __restrict__ vcent,
    const float* __restrict__ sval, const int* __restrict__ sidx,
    float* __restrict__ agg)
{
  const int bh = blockIdx.x;
  const int b = bh >> 3, h = bh & 7;
  __shared__ float acc[384];
  __shared__ float cnt[16];
  for (int i = threadIdx.x; i < 384; i += 256) acc[i] = 0.f;
  if (threadIdx.x < 16) cnt[threadIdx.x] = 0.f;
  __syncthreads();
  for (int n = threadIdx.x; n < 1024; n += 256) {
    const float s = sval[(size_t)bh * 1024 + n];
    const int m = sidx[(size_t)bh * 1024 + n];
    atomicAdd(&cnt[m], 1.0f);
    const float* vv = val + (size_t)(b * 1024 + n) * 192 + h * 24;
#pragma unroll
    for (int k = 0; k < 24; ++k) atomicAdd(&acc[m * 24 + k], s * vv[k]);
  }
  __syncthreads();
  for (int i = threadIdx.x; i < 384; i += 256) {
    const int m = i / 24;
    agg[(size_t)bh * 384 + i] = (acc[i] + vcent[(size_t)bh * 384 + i]) / (cnt[m] + 1.0f);
  }
}

// ---------------------------------------------------------------------------
// o[b,n,h*24+c] = s_n * agg[bh, idx_n, c]   (bf16 out, thread per (b,n,h))
__global__ __launch_bounds__(256) void dispatch_kernel(
    const float* __restrict__ sval, const int* __restrict__ sidx,
    const float* __restrict__ agg, short* __restrict__ o)
{
  const int g = blockIdx.x * 256 + threadIdx.x;      // b*8192 + n*8 + h
  const int h = g & 7, n = (g >> 3) & 1023, b = g >> 13;
  const int bh = b * 8 + h;
  const float s = sval[(size_t)bh * 1024 + n];
  const int m = sidx[(size_t)bh * 1024 + n];
  const float* a = agg + (size_t)bh * 384 + m * 24;
  short* op = o + ((size_t)(b * 1024 + n)) * 192 + h * 24;
  short8 pack[3];
#pragma unroll
  for (int k = 0; k < 24; ++k) pack[k >> 3][k & 7] = f2bf(s * a[k]);
  short8* dst = reinterpret_cast<short8*>(op);
  dst[0] = pack[0]; dst[1] = pack[1]; dst[2] = pack[2];
}

// ---------------------------------------------------------------------------
extern "C" void kernel_launch(void* const* d_in, const int* in_sizes, int n_in,
                              void* d_out, int out_size, void* d_ws, size_t ws_size,
                              hipStream_t stream)
{
  const float* x      = (const float*)d_in[0];
  const float* ln1_g  = (const float*)d_in[1];
  const float* ln1_b  = (const float*)d_in[2];
  const float* f_w    = (const float*)d_in[3];
  const float* f_b    = (const float*)d_in[4];
  const float* v_w    = (const float*)d_in[5];
  const float* v_b    = (const float*)d_in[6];
  const float* alpha  = (const float*)d_in[7];
  const float* beta   = (const float*)d_in[8];
  const float* proj_w = (const float*)d_in[9];
  const float* proj_b = (const float*)d_in[10];
  const float* ln2_g  = (const float*)d_in[11];
  const float* ln2_b  = (const float*)d_in[12];
  const float* fc1_w  = (const float*)d_in[13];
  const float* fc1_b  = (const float*)d_in[14];
  const float* fc2_w  = (const float*)d_in[15];
  const float* fc2_b  = (const float*)d_in[16];
  float* out = (float*)d_out;

  char* ws = (char*)d_ws;
  size_t off = 0;
  auto alloc = [&](size_t bytes) -> char* {
    char* p = ws + off;
    off = (off + bytes + 255) & ~(size_t)255;
    return p;
  };
  // base ~339 MB; fresh h1 (+134 MB -> 2 chunks) if ws allows (round-4 proven)
  short* xn   = (short*)alloc(67108864);    // LN1 out, bf16 [65536,512]
  float* feat = (float*)alloc(50331648);    // f32 [65536,192]
  float* val  = (float*)alloc(50331648);    // f32 [65536,192]
  short* o    = (short*)alloc(25165824);    // bf16 [65536,192]
  float* x1   = (float*)alloc(134217728);   // f32 [65536,512] residual stream
  short* wf   = (short*)alloc(196608);
  short* wv   = (short*)alloc(196608);
  short* wp   = (short*)alloc(196608);
  short* w1   = (short*)alloc(2097152);
  short* w2   = (short*)alloc(2097152);
  float* cnb  = (float*)alloc(786432);      // [512,16,24]
  float* vcb  = (float*)alloc(786432);
  float* agb  = (float*)alloc(786432);
  float* svb  = (float*)alloc(2097152);     // [512,1024]
  int*   sib  = (int*)  alloc(2097152);
  short* h  = (short*)feat;                 // LN2 out bf16 [65536,512] (aliases feat+val)

  const size_t h1_bytes = 134217728;        // [32768,2048] bf16
  short* h1;
  int nchunk;
  if (ws_size >= off + h1_bytes) {
    h1 = (short*)alloc(h1_bytes);
    nchunk = 2;
  } else {
    h1 = xn;                                // [16384,2048] fits xn's 64 MB
    nchunk = 4;
  }
  const int MCH = 65536 / nchunk;

  // weight conversions
  cvt_f32_bf16<<<96,   256, 0, stream>>>(f_w,    wf, 24576);
  cvt_f32_bf16<<<96,   256, 0, stream>>>(v_w,    wv, 24576);
  cvt_f32_bf16<<<96,   256, 0, stream>>>(proj_w, wp, 24576);
  cvt_f32_bf16<<<1024, 256, 0, stream>>>(fc1_w,  w1, 262144);
  cvt_f32_bf16<<<1024, 256, 0, stream>>>(fc2_w,  w2, 262144);

  // 1. xn = LN1(x)
  ln_kernel<<<16384, 256, 0, stream>>>(x, ln1_g, ln1_b, xn);

  // 2. feat/val = xn @ {f,v}_w^T + bias    [65536,192] f32  (round-3/4 config)
  gemm_bt<256, 64, 64, 64, 0><<<dim3(256, 3), 256, 0, stream>>>(
      xn, wf, f_b, nullptr, feat, nullptr, 192, 512);
  gemm_bt<256, 64, 64, 64, 0><<<dim3(256, 3), 256, 0, stream>>>(
      xn, wv, v_b, nullptr, val, nullptr, 192, 512);

  // 3. cluster centers + normalize
  pool_kernel<<<512, 384, 0, stream>>>(feat, val, cnb, vcb);
  // 4. sim + leaky + top-1
  sim_kernel<<<dim3(4, 512), 256, 0, stream>>>(feat, cnb, alpha, beta, svb, sib);
  // 5. aggregate into centers
  agg_kernel<<<512, 256, 0, stream>>>(val, vcb, svb, sib, agb);
  // 6. dispatch back to tokens (bf16)
  dispatch_kernel<<<2048, 256, 0, stream>>>(svb, sib, agb, o);

  // 7. x1 = x + o @ proj_w^T + proj_b   (round-3/4 config)
  gemm_bt<128, 128, 64, 64, 1><<<dim3(512, 4), 256, 0, stream>>>(
      o, wp, proj_b, x, x1, nullptr, 512, 192);

  // 8. h = LN2(x1)  (bf16)
  ln_kernel<<<16384, 256, 0, stream>>>(x1, ln2_g, ln2_b, h);

  // 9/10. MLP on 256x256 tiles (gemm512), nchunk row-chunks of MCH
  //   fc1: K=512  (nt=16), grid (MCH/256, 8)
  //   fc2: K=2048 (nt=64), grid (MCH/256, 2)
  for (int c = 0; c < nchunk; ++c) {
    const short* hA = h + (size_t)c * MCH * 512;
    gemm512<2><<<dim3(MCH / 256, 8), 512, 0, stream>>>(
        hA, w1, fc1_b, nullptr, nullptr, h1, 2048, 512);
    gemm512<1><<<dim3(MCH / 256, 2), 512, 0, stream>>>(
        h1, w2, fc2_b, x1 + (size_t)c * MCH * 512,
        out + (size_t)c * MCH * 512, nullptr, 512, 2048);
  }
  (void)in_sizes; (void)n_in; (void)out_size;
}

// Round 7
// 1002.863 us; speedup vs baseline: 1.1803x; 1.1803x over previous
//
#include <hip/hip_runtime.h>

// ---------------------------------------------------------------------------
// SClusterFormer block for MI355X (gfx950).
// Round 7: deep-pipelined 256x256 MLP GEMM (triple-buffer + counted vmcnt).
//   - gemm_deep: BM=BN=256, BK=32, 512 thr (8 waves 2Mx4N, wave tile 128x64),
//     3 LDS K-tile buffers (96 KB DYNAMIC shared, hipFuncSetAttribute),
//     per K-tile: vmcnt(8) [2 tiles stay in flight] -> s_barrier ->
//     ds_read x12 -> lgkmcnt(0) -> 32 MFMA (setprio 1) -> s_barrier ->
//     stage(t+3). Stage-to-consume distance = 2 K-tiles (~2800cy >> HBM lat).
//   - fc1/fc2 single-shot (grid 2048 / 512 blocks) when workspace allows.
//   - attribute-failure fallback: round-3-proven gemm_bt 128^2 MLP.
//   - all non-MLP stages identical to round 3 (best passing config).
// ---------------------------------------------------------------------------

typedef __attribute__((ext_vector_type(8))) short short8;
typedef __attribute__((ext_vector_type(4))) short short4v;
typedef __attribute__((ext_vector_type(4))) float floatx4;

// float -> bf16 bits, round-to-nearest-even (inputs finite)
static __device__ __forceinline__ short f2bf(float f) {
  union { float f; unsigned u; } a; a.f = f;
  unsigned r = a.u + 0x7fffu + ((a.u >> 16) & 1u);
  return (short)(r >> 16);
}

// async global->LDS, 16 bytes per lane. LDS dest must be wave-uniform base +
// lane*16 (our staging index is lane-contiguous per wave, so this holds).
static __device__ __forceinline__ void gload_lds16(const short* g, short* l) {
  __builtin_amdgcn_global_load_lds(
      (const __attribute__((address_space(1))) void*)g,
      (__attribute__((address_space(3))) void*)l, 16, 0, 0);
}

// ---------------------------------------------------------------------------
// f32 -> bf16 weight conversion (elementwise, float4 per thread)
__global__ __launch_bounds__(256) void cvt_f32_bf16(
    const float* __restrict__ in, short* __restrict__ out, int n4)
{
  int i = blockIdx.x * 256 + threadIdx.x;
  if (i >= n4) return;
  float4 v = reinterpret_cast<const float4*>(in)[i];
  short4v o;
  o[0] = f2bf(v.x); o[1] = f2bf(v.y); o[2] = f2bf(v.z); o[3] = f2bf(v.w);
  reinterpret_cast<short4v*>(out)[i] = o;
}

// ---------------------------------------------------------------------------
// LayerNorm over D=512, one wave per row, bf16 output.
__global__ __launch_bounds__(256) void ln_kernel(
    const float* __restrict__ x, const float* __restrict__ g,
    const float* __restrict__ b, short* __restrict__ out)
{
  const int wave = threadIdx.x >> 6, lane = threadIdx.x & 63;
  const size_t row = (size_t)blockIdx.x * 4 + wave;
  const float* xr = x + row * 512;
  const int c = lane * 8;
  float4 v0 = *reinterpret_cast<const float4*>(xr + c);
  float4 v1 = *reinterpret_cast<const float4*>(xr + c + 4);
  float xs[8] = {v0.x, v0.y, v0.z, v0.w, v1.x, v1.y, v1.z, v1.w};
  float s = 0.f, q = 0.f;
#pragma unroll
  for (int k = 0; k < 8; ++k) { s += xs[k]; q += xs[k] * xs[k]; }
#pragma unroll
  for (int off = 32; off; off >>= 1) {
    s += __shfl_xor(s, off);
    q += __shfl_xor(q, off);
  }
  const float mean = s * (1.0f / 512.0f);
  const float var  = q * (1.0f / 512.0f) - mean * mean;
  const float rstd = rsqrtf(var + 1e-5f);
  short8 o;
#pragma unroll
  for (int k = 0; k < 8; ++k)
    o[k] = f2bf((xs[k] - mean) * rstd * g[c + k] + b[c + k]);
  *reinterpret_cast<short8*>(out + row * 512 + c) = o;
}

// ---------------------------------------------------------------------------
// gemm_bt (4-wave, 2-phase dbuf): round-3 proven form.
//   EPI 0: store f32   EPI 1: +resid, store f32   EPI 2: gelu, store bf16
template<int BM, int BN, int WM, int WN, int EPI>
__global__ __launch_bounds__(256, 2) void gemm_bt(
    const short* __restrict__ A, const short* __restrict__ W,
    const float* __restrict__ bias, const float* __restrict__ resid,
    float* __restrict__ Cf, short* __restrict__ Cb,
    const int N, const int K)
{
  constexpr int BK = 32;
  constexpr int T  = 256;
  constexpr int AC = (BM * BK / 8) / T;
  constexpr int WC = (BN * BK / 8) / T;
  __shared__ short Al[2][BM * BK];
  __shared__ short Wl[2][BN * BK];
  const int tid  = threadIdx.x;
  const int wave = tid >> 6;
  const int lane = tid & 63;
  constexpr int WCOLS = BN / WN;
  const int wm = (wave / WCOLS) * WM;
  const int wn = (wave % WCOLS) * WN;
  constexpr int MI = WM / 16, NJ = WN / 16;
  const int row0 = blockIdx.x * BM;
  const int col0 = blockIdx.y * BN;
  const int r  = lane & 15;
  const int kc = lane >> 4;

  floatx4 acc[MI][NJ];
#pragma unroll
  for (int i = 0; i < MI; ++i)
#pragma unroll
    for (int j = 0; j < NJ; ++j)
      acc[i][j] = (floatx4){0.f, 0.f, 0.f, 0.f};

  const short* Ab = A + (size_t)row0 * K;
  const short* Wb = W + (size_t)col0 * K;

  const short* aSrc[AC]; int aDst[AC];
#pragma unroll
  for (int u = 0; u < AC; ++u) {
    const int cc = u * T + tid;
    const int rr = cc >> 2, sl = cc & 3;
    const int co = sl ^ ((rr >> 1) & 3);
    aSrc[u] = Ab + (size_t)rr * K + co * 8;
    aDst[u] = cc * 8;
  }
  const short* wSrc[WC]; int wDst[WC];
#pragma unroll
  for (int u = 0; u < WC; ++u) {
    const int cc = u * T + tid;
    const int rr = cc >> 2, sl = cc & 3;
    const int co = sl ^ ((rr >> 1) & 3);
    wSrc[u] = Wb + (size_t)rr * K + co * 8;
    wDst[u] = cc * 8;
  }
  int aOff[MI], wOff[NJ];
#pragma unroll
  for (int i = 0; i < MI; ++i) {
    const int rt = wm + 16 * i + r;
    aOff[i] = rt * BK + ((kc ^ ((rt >> 1) & 3)) << 3);
  }
#pragma unroll
  for (int j = 0; j < NJ; ++j) {
    const int rt = wn + 16 * j + r;
    wOff[j] = rt * BK + ((kc ^ ((rt >> 1) & 3)) << 3);
  }

  auto stage = [&](int buf, int k0) {
#pragma unroll
    for (int u = 0; u < AC; ++u) gload_lds16(aSrc[u] + k0, &Al[buf][aDst[u]]);
#pragma unroll
    for (int u = 0; u < WC; ++u) gload_lds16(wSrc[u] + k0, &Wl[buf][wDst[u]]);
  };

  stage(0, 0);
  __syncthreads();
  int cur = 0;
  for (int k0 = BK; k0 <= K; k0 += BK) {
    if (k0 < K) stage(cur ^ 1, k0);
    short8 af[MI], wfr[NJ];
#pragma unroll
    for (int i = 0; i < MI; ++i)
      af[i] = *reinterpret_cast<const short8*>(&Al[cur][aOff[i]]);
#pragma unroll
    for (int j = 0; j < NJ; ++j)
      wfr[j] = *reinterpret_cast<const short8*>(&Wl[cur][wOff[j]]);
#pragma unroll
    for (int i = 0; i < MI; ++i)
#pragma unroll
      for (int j = 0; j < NJ; ++j)
        acc[i][j] = __builtin_amdgcn_mfma_f32_16x16x32_bf16(
            af[i], wfr[j], acc[i][j], 0, 0, 0);
    __syncthreads();
    cur ^= 1;
  }

#pragma unroll
  for (int i = 0; i < MI; ++i) {
#pragma unroll
    for (int j = 0; j < NJ; ++j) {
      const int col = col0 + wn + 16 * j + r;
      const float bv = bias[col];
#pragma unroll
      for (int t = 0; t < 4; ++t) {
        const int rowi = row0 + wm + 16 * i + (lane >> 4) * 4 + t;
        const size_t offo = (size_t)rowi * N + col;
        float v = acc[i][j][t] + bv;
        if (EPI == 0) {
          Cf[offo] = v;
        } else if (EPI == 1) {
          Cf[offo] = v + resid[offo];
        } else {
          v = 0.5f * v * (1.0f + erff(v * 0.70710678118654752f));
          Cb[offo] = f2bf(v);
        }
      }
    }
  }
}

// ---------------------------------------------------------------------------
// gemm_deep (8-wave, triple-buffer, counted vmcnt): 256x256, BK=32, wave tile
// 128x64 (MI=8, NJ=4). Dynamic LDS = 3 bufs x (8192 A + 8192 W) shorts = 96KB.
// Per K-tile t: vmcnt(8) [tiles t+1,t+2 stay in flight] -> s_barrier ->
// ds_read x12 -> lgkmcnt(0) -> 32 MFMA -> s_barrier -> stage(t+3).
// Requires K/BK >= 3. EPI 1: +resid f32; EPI 2: gelu bf16.
template<int EPI>
__global__ __launch_bounds__(512, 1) void gemm_deep(
    const short* __restrict__ A, const short* __restrict__ W,
    const float* __restrict__ bias, const float* __restrict__ resid,
    float* __restrict__ Cf, short* __restrict__ Cb,
    const int N, const int K)
{
  constexpr int BM = 256, BN = 256, BK = 32;
  constexpr int BUF = BM * BK;            // 8192 shorts per matrix per buf
  extern __shared__ short lds[];          // 3 * 2 * BUF shorts = 96 KiB
  const int tid  = threadIdx.x;           // 0..511
  const int wave = tid >> 6;
  const int lane = tid & 63;
  const int wm = (wave >> 2) * 128;
  const int wn = (wave & 3) * 64;
  const int row0 = blockIdx.x * BM;
  const int col0 = blockIdx.y * BN;
  const int r  = lane & 15;
  const int kc = lane >> 4;

  floatx4 acc[8][4];
#pragma unroll
  for (int i = 0; i < 8; ++i)
#pragma unroll
    for (int j = 0; j < 4; ++j)
      acc[i][j] = (floatx4){0.f, 0.f, 0.f, 0.f};

  const short* Ab = A + (size_t)row0 * K;
  const short* Wb = W + (size_t)col0 * K;

  // staging: 1024 chunks of 16B per matrix per tile -> 2/thread each
  const short* aSrc[2]; const short* wSrc[2]; int dstO[2];
#pragma unroll
  for (int u = 0; u < 2; ++u) {
    const int cc = u * 512 + tid;
    const int rr = cc >> 2, sl = cc & 3;
    const int co = sl ^ ((rr >> 1) & 3);
    aSrc[u] = Ab + (size_t)rr * K + co * 8;
    wSrc[u] = Wb + (size_t)rr * K + co * 8;
    dstO[u] = cc * 8;
  }
  int aOff[8], wOff[4];
#pragma unroll
  for (int i = 0; i < 8; ++i) {
    const int rt = wm + 16 * i + r;
    aOff[i] = rt * BK + ((kc ^ ((rt >> 1) & 3)) << 3);
  }
#pragma unroll
  for (int j = 0; j < 4; ++j) {
    const int rt = wn + 16 * j + r;
    wOff[j] = rt * BK + ((kc ^ ((rt >> 1) & 3)) << 3);
  }

  auto stage = [&](int buf, int k0) {
    short* base = lds + buf * (2 * BUF);
#pragma unroll
    for (int u = 0; u < 2; ++u) gload_lds16(aSrc[u] + k0, base + dstO[u]);
#pragma unroll
    for (int u = 0; u < 2; ++u) gload_lds16(wSrc[u] + k0, base + BUF + dstO[u]);
  };

  const int nt = K / BK;                  // >= 3 (fc1: 16, fc2: 64)
  stage(0, 0);
  stage(1, BK);
  stage(2, 2 * BK);
  int cur = 0;
  for (int t = 0; t < nt; ++t) {
    // tile t landed once <= 8 loads outstanding (in-order retirement);
    // tiles t+1, t+2 (4 loads each) remain in flight across the barrier.
    asm volatile("s_waitcnt vmcnt(8)" ::: "memory");
    __builtin_amdgcn_s_barrier();         // cross-wave tile-t writes visible
    __builtin_amdgcn_sched_barrier(0);    // ds_reads must not hoist above
    const short* base = lds + cur * (2 * BUF);
    short8 af[8], wf[4];
#pragma unroll
    for (int i = 0; i < 8; ++i)
      af[i] = *reinterpret_cast<const short8*>(base + aOff[i]);
#pragma unroll
    for (int j = 0; j < 4; ++j)
      wf[j] = *reinterpret_cast<const short8*>(base + BUF + wOff[j]);
    asm volatile("s_waitcnt lgkmcnt(0)" ::: "memory");
    __builtin_amdgcn_sched_barrier(0);    // rule 18: MFMA stays below the wait
    __builtin_amdgcn_s_setprio(1);
#pragma unroll
    for (int i = 0; i < 8; ++i)
#pragma unroll
      for (int j = 0; j < 4; ++j)
        acc[i][j] = __builtin_amdgcn_mfma_f32_16x16x32_bf16(
            af[i], wf[j], acc[i][j], 0, 0, 0);
    __builtin_amdgcn_s_setprio(0);
    __builtin_amdgcn_sched_barrier(0);
    __builtin_amdgcn_s_barrier();         // all waves done reading buf[cur]
    if (t + 3 < nt) stage(cur, (t + 3) * BK);
    cur = (cur == 2) ? 0 : cur + 1;
  }

  // epilogue: col=lane&15, row=(lane>>4)*4+reg  (identical to passing gemm512)
#pragma unroll
  for (int i = 0; i < 8; ++i) {
#pragma unroll
    for (int j = 0; j < 4; ++j) {
      const int col = col0 + wn + 16 * j + r;
      const float bv = bias[col];
#pragma unroll
      for (int tt = 0; tt < 4; ++tt) {
        const int rowi = row0 + wm + 16 * i + kc * 4 + tt;
        const size_t offo = (size_t)rowi * N + col;
        float v = acc[i][j][tt] + bv;
        if (EPI == 1) {
          Cf[offo] = v + resid[offo];
        } else {
          v = 0.5f * v * (1.0f + erff(v * 0.70710678118654752f));
          Cb[offo] = f2bf(v);
        }
      }
    }
  }
}

// ---------------------------------------------------------------------------
// AdaptiveAvgPool 32x32 -> 4x4 per (b,h); writes normalized centers (cn) and
// pooled values (vcent). One block per bh, 384 threads = (m, c).
__global__ __launch_bounds__(384) void pool_kernel(
    const float* __restrict__ feat, const float* __restrict__ val,
    float* __restrict__ cn, float* __restrict__ vcent)
{
  const int bh = blockIdx.x;
  const int b = bh >> 3, h = bh & 7;
  const int t = threadIdx.x;        // 0..383
  const int m = t / 24, c = t % 24;
  const int cy = m >> 2, cx = m & 3;
  const size_t base = (size_t)b * 1024 * 192 + h * 24 + c;
  float sf = 0.f, sv = 0.f;
  for (int dy = 0; dy < 8; ++dy) {
    const int ny = (cy * 8 + dy) * 32 + cx * 8;
    for (int dx = 0; dx < 8; ++dx) {
      const size_t off = base + (size_t)(ny + dx) * 192;
      sf += feat[off];
      sv += val[off];
    }
  }
  sf *= (1.0f / 64.0f); sv *= (1.0f / 64.0f);
  __shared__ float cent[16][24];
  cent[m][c] = sf;
  vcent[(size_t)bh * 384 + t] = sv;
  __syncthreads();
  float nrm = 0.f;
#pragma unroll
  for (int k = 0; k < 24; ++k) nrm += cent[m][k] * cent[m][k];
  nrm = fmaxf(sqrtf(nrm), 1e-12f);
  cn[(size_t)bh * 384 + t] = sf / nrm;
}

// ---------------------------------------------------------------------------
// Per token: cosine sim vs 16 centers, leaky-relu, top-1 -> (value, index).
__global__ __launch_bounds__(256) void sim_kernel(
    const float* __restrict__ feat, const float* __restrict__ cn,
    const float* __restrict__ alpha_p, const float* __restrict__ beta_p,
    float* __restrict__ sval, int* __restrict__ sidx)
{
  const int bh = blockIdx.y;
  const int b = bh >> 3, h = bh & 7;
  __shared__ float cs[384];
  for (int i = threadIdx.x; i < 384; i += 256) cs[i] = cn[(size_t)bh * 384 + i];
  __syncthreads();
  const int n = blockIdx.x * 256 + threadIdx.x;
  const float* f = feat + (size_t)(b * 1024 + n) * 192 + h * 24;
  float v[24];
#pragma unroll
  for (int k = 0; k < 24; k += 4) {
    float4 t4 = *reinterpret_cast<const float4*>(f + k);
    v[k] = t4.x; v[k + 1] = t4.y; v[k + 2] = t4.z; v[k + 3] = t4.w;
  }
  float q = 0.f;
#pragma unroll
  for (int k = 0; k < 24; ++k) q += v[k] * v[k];
  const float inv = 1.0f / fmaxf(sqrtf(q), 1e-12f);
  const float alpha = alpha_p[0], beta = beta_p[0];
  float best = -3.4e38f; int bi = 0;
#pragma unroll
  for (int m = 0; m < 16; ++m) {
    float d = 0.f;
#pragma unroll
    for (int k = 0; k < 24; ++k) d += cs[m * 24 + k] * v[k];
    float s = beta + alpha * (d * inv);
    s = (s < 0.f) ? 0.2f * s : s;            // LeakyReLU(0.2)
    if (s > best) { best = s; bi = m; }      // strict > == first-max (jnp.argmax)
  }
  sval[(size_t)bh * 1024 + n] = best;
  sidx[(size_t)bh * 1024 + n] = bi;
}

// ---------------------------------------------------------------------------
// agg[bh,m,:] = (sum_{n: idx=m} s_n * vh[n,:] + vcent[m,:]) / (count_m + 1)
__global__ __launch_bounds__(256) void agg_kernel(
    const float* __restrict__ val, const float* __restrict__ vcent,
    const float* __restrict__ sval, const int* __restrict__ sidx,
    float* __restrict__ agg)
{
  const int bh = blockIdx.x;
  const int b = bh >> 3, h = bh & 7;
  __shared__ float acc[384];
  __shared__ float cnt[16];
  for (int i = threadIdx.x; i < 384; i += 256) acc[i] = 0.f;
  if (threadIdx.x < 16) cnt[threadIdx.x] = 0.f;
  __syncthreads();
  for (int n = threadIdx.x; n < 1024; n += 256) {
    const float s = sval[(size_t)bh * 1024 + n];
    const int m = sidx[(size_t)bh * 1024 + n];
    atomicAdd(&cnt[m], 1.0f);
    const float* vv = val + (size_t)(b * 1024 + n) * 192 + h * 24;
#pragma unroll
    for (int k = 0; k < 24; ++k) atomicAdd(&acc[m * 24 + k], s * vv[k]);
  }
  __syncthreads();
  for (int i = threadIdx.x; i < 384; i += 256) {
    const int m = i / 24;
    agg[(size_t)bh * 384 + i] = (acc[i] + vcent[(size_t)bh * 384 + i]) / (cnt[m] + 1.0f);
  }
}

// ---------------------------------------------------------------------------
// o[b,n,h*24+c] = s_n * agg[bh, idx_n, c]   (bf16 out, thread per (b,n,h))
__global__ __launch_bounds__(256) void dispatch_kernel(
    const float* __restrict__ sval, const int* __restrict__ sidx,
    const float* __restrict__ agg, short* __restrict__ o)
{
  const int g = blockIdx.x * 256 + threadIdx.x;      // b*8192 + n*8 + h
  const int h = g & 7, n = (g >> 3) & 1023, b = g >> 13;
  const int bh = b * 8 + h;
  const float s = sval[(size_t)bh * 1024 + n];
  const int m = sidx[(size_t)bh * 1024 + n];
  const float* a = agg + (size_t)bh * 384 + m * 24;
  short* op = o + ((size_t)(b * 1024 + n)) * 192 + h * 24;
  short8 pack[3];
#pragma unroll
  for (int k = 0; k < 24; ++k) pack[k >> 3][k & 7] = f2bf(s * a[k]);
  short8* dst = reinterpret_cast<short8*>(op);
  dst[0] = pack[0]; dst[1] = pack[1]; dst[2] = pack[2];
}

// ---------------------------------------------------------------------------
extern "C" void kernel_launch(void* const* d_in, const int* in_sizes, int n_in,
                              void* d_out, int out_size, void* d_ws, size_t ws_size,
                              hipStream_t stream)
{
  const float* x      = (const float*)d_in[0];
  const float* ln1_g  = (const float*)d_in[1];
  const float* ln1_b  = (const float*)d_in[2];
  const float* f_w    = (const float*)d_in[3];
  const float* f_b    = (const float*)d_in[4];
  const float* v_w    = (const float*)d_in[5];
  const float* v_b    = (const float*)d_in[6];
  const float* alpha  = (const float*)d_in[7];
  const float* beta   = (const float*)d_in[8];
  const float* proj_w = (const float*)d_in[9];
  const float* proj_b = (const float*)d_in[10];
  const float* ln2_g  = (const float*)d_in[11];
  const float* ln2_b  = (const float*)d_in[12];
  const float* fc1_w  = (const float*)d_in[13];
  const float* fc1_b  = (const float*)d_in[14];
  const float* fc2_w  = (const float*)d_in[15];
  const float* fc2_b  = (const float*)d_in[16];
  float* out = (float*)d_out;

  char* ws = (char*)d_ws;
  size_t off = 0;
  auto alloc = [&](size_t bytes) -> char* {
    char* p = ws + off;
    off = (off + bytes + 255) & ~(size_t)255;
    return p;
  };
  // base ~339 MB; h1 tiered by available workspace
  short* xn   = (short*)alloc(67108864);    // LN1 out, bf16 [65536,512]
  float* feat = (float*)alloc(50331648);    // f32 [65536,192]
  float* val  = (float*)alloc(50331648);    // f32 [65536,192]
  short* o    = (short*)alloc(25165824);    // bf16 [65536,192]
  float* x1   = (float*)alloc(134217728);   // f32 [65536,512] residual stream
  short* wf   = (short*)alloc(196608);
  short* wv   = (short*)alloc(196608);
  short* wp   = (short*)alloc(196608);
  short* w1   = (short*)alloc(2097152);
  short* w2   = (short*)alloc(2097152);
  float* cnb  = (float*)alloc(786432);      // [512,16,24]
  float* vcb  = (float*)alloc(786432);
  float* agb  = (float*)alloc(786432);
  float* svb  = (float*)alloc(2097152);     // [512,1024]
  int*   sib  = (int*)  alloc(2097152);
  short* h  = (short*)feat;                 // LN2 out bf16 [65536,512] (aliases feat+val)

  // h1 tier: full 268 MB (1 chunk) > 134 MB (2 chunks) > alias xn (4 chunks)
  short* h1;
  int nchunk;
  if (ws_size >= off + 268435456) {
    h1 = (short*)alloc(268435456);
    nchunk = 1;
  } else if (ws_size >= off + 134217728) {
    h1 = (short*)alloc(134217728);
    nchunk = 2;
  } else {
    h1 = xn;
    nchunk = 4;
  }
  const int MCH = 65536 / nchunk;

  // enable 96 KB dynamic LDS for gemm_deep; fall back to gemm_bt MLP on error
  hipError_t e1 = hipFuncSetAttribute(
      reinterpret_cast<const void*>(gemm_deep<2>),
      hipFuncAttributeMaxDynamicSharedMemorySize, 98304);
  hipError_t e2 = hipFuncSetAttribute(
      reinterpret_cast<const void*>(gemm_deep<1>),
      hipFuncAttributeMaxDynamicSharedMemorySize, 98304);
  const bool deep = (e1 == hipSuccess) && (e2 == hipSuccess) && (MCH % 256 == 0);

  // weight conversions
  cvt_f32_bf16<<<96,   256, 0, stream>>>(f_w,    wf, 24576);
  cvt_f32_bf16<<<96,   256, 0, stream>>>(v_w,    wv, 24576);
  cvt_f32_bf16<<<96,   256, 0, stream>>>(proj_w, wp, 24576);
  cvt_f32_bf16<<<1024, 256, 0, stream>>>(fc1_w,  w1, 262144);
  cvt_f32_bf16<<<1024, 256, 0, stream>>>(fc2_w,  w2, 262144);

  // 1. xn = LN1(x)
  ln_kernel<<<16384, 256, 0, stream>>>(x, ln1_g, ln1_b, xn);

  // 2. feat/val = xn @ {f,v}_w^T + bias    [65536,192] f32  (round-3 config)
  gemm_bt<256, 64, 64, 64, 0><<<dim3(256, 3), 256, 0, stream>>>(
      xn, wf, f_b, nullptr, feat, nullptr, 192, 512);
  gemm_bt<256, 64, 64, 64, 0><<<dim3(256, 3), 256, 0, stream>>>(
      xn, wv, v_b, nullptr, val, nullptr, 192, 512);

  // 3. cluster centers + normalize
  pool_kernel<<<512, 384, 0, stream>>>(feat, val, cnb, vcb);
  // 4. sim + leaky + top-1
  sim_kernel<<<dim3(4, 512), 256, 0, stream>>>(feat, cnb, alpha, beta, svb, sib);
  // 5. aggregate into centers
  agg_kernel<<<512, 256, 0, stream>>>(val, vcb, svb, sib, agb);
  // 6. dispatch back to tokens (bf16)
  dispatch_kernel<<<2048, 256, 0, stream>>>(svb, sib, agb, o);

  // 7. x1 = x + o @ proj_w^T + proj_b   (round-3 config)
  gemm_bt<128, 128, 64, 64, 1><<<dim3(512, 4), 256, 0, stream>>>(
      o, wp, proj_b, x, x1, nullptr, 512, 192);

  // 8. h = LN2(x1)  (bf16)
  ln_kernel<<<16384, 256, 0, stream>>>(x1, ln2_g, ln2_b, h);

  // 9/10. MLP in nchunk row-chunks of MCH
  for (int c = 0; c < nchunk; ++c) {
    const short* hA = h + (size_t)c * MCH * 512;
    float* x1c = x1 + (size_t)c * MCH * 512;
    float* outc = out + (size_t)c * MCH * 512;
    if (deep) {
      // fc1: K=512 (nt=16), grid (MCH/256, 8); fc2: K=2048 (nt=64), (MCH/256, 2)
      gemm_deep<2><<<dim3(MCH / 256, 8), 512, 98304, stream>>>(
          hA, w1, fc1_b, nullptr, nullptr, h1, 2048, 512);
      gemm_deep<1><<<dim3(MCH / 256, 2), 512, 98304, stream>>>(
          h1, w2, fc2_b, x1c, outc, nullptr, 512, 2048);
    } else {
      gemm_bt<128, 128, 64, 64, 2><<<dim3(MCH / 128, 16), 256, 0, stream>>>(
          hA, w1, fc1_b, nullptr, nullptr, h1, 2048, 512);
      gemm_bt<128, 128, 64, 64, 1><<<dim3(MCH / 128, 4), 256, 0, stream>>>(
          h1, w2, fc2_b, x1c, outc, nullptr, 512, 2048);
    }
  }
  (void)in_sizes; (void)n_in; (void)out_size;
}